// Round 1
// baseline (204.499 us; speedup 1.0000x reference)
//
#include <hip/hip_runtime.h>
#include <hip/hip_bf16.h>

// B=4, T=4096, C=1024, H=64 causal attention w/ RPE bias.
// Round 10: flash_part was stall-bound (MfmaUtil 6.5%, VALUBusy 26%, occ 23%):
// per-wave global K/V streaming (~540 MB TA traffic) with a vmcnt(0)-defeated
// prefetch put an L2 round trip on every 32-key step. Restructure: batch ->
// blockIdx.z, 8 waves = 8 query-substrips of ONE batch sharing a 256-key
// chunk staged ONCE into LDS via async global_load_lds (kfrag/vfrag are
// fragment-linear -> lds-dest-compatible + conflict-free ds_read_b128).
// Bias: per-step double-buffered register prefetch from global (fp32,
// bit-identical). k-loop critical path now has zero global loads.

#define T_DIM 4096
#define C_DIM 1024
#define CK    256          // flash key-chunk (keys per po partial)

typedef __attribute__((ext_vector_type(8))) short s16x8;
typedef __attribute__((ext_vector_type(4))) float f32x4;
typedef __attribute__((ext_vector_type(2))) unsigned int u32x2;

__device__ __forceinline__ short f2bf(float f) {
    unsigned u = __builtin_bit_cast(unsigned, f);
    u += 0x7FFFu + ((u >> 16) & 1u);
    return (short)(u >> 16);
}
__device__ __forceinline__ unsigned pack2(float a, float b) {
    unsigned ua = __builtin_bit_cast(unsigned, a);
    unsigned ub = __builtin_bit_cast(unsigned, b);
    ua += 0x7FFFu + ((ua >> 16) & 1u);
    ub += 0x7FFFu + ((ub >> 16) & 1u);
    return __builtin_amdgcn_perm(ub, ua, 0x07060302u);
}
__device__ __forceinline__ float bf2f(short s) {
    unsigned u = ((unsigned)(unsigned short)s) << 16;
    return __builtin_bit_cast(float, u);
}
// prefix of active 256-key chunks before 16-q-strip qt: nchunks(j)=j/16+1
__device__ __forceinline__ int chunk_off(int qt) {
    int g = qt >> 4, r = qt & 15;
    return qt + 8 * g * (g - 1) + r * g;
}
// async 16B global->LDS (lds dest = wave-uniform base + lane*16)
__device__ __forceinline__ void async16(const short* g, short* l) {
    __builtin_amdgcn_global_load_lds(
        (const __attribute__((address_space(1))) unsigned int*)g,
        (__attribute__((address_space(3))) unsigned int*)l, 16, 0, 0);
}

// ---------------------------------------------------------------------------
// Kernel 1: weights -> B-fragment order: wfrag[ksAll][mat][nt][lane][8] bf16.
// w_q scaled by 0.125. grid (32, 3) x 256.
// ---------------------------------------------------------------------------
__global__ __launch_bounds__(256) void prep_frag(
    const float* __restrict__ wk, const float* __restrict__ wq,
    const float* __restrict__ wv, short* __restrict__ wfrag)
{
    int ksAll = blockIdx.x, mat = blockIdx.y;
    const float* w = (mat == 0) ? wk : ((mat == 1) ? wq : wv);
    float sc = (mat == 1) ? 0.125f : 1.0f;
    int nt = threadIdx.x >> 6, lane = threadIdx.x & 63;
    int quad = lane >> 4, l15 = lane & 15;
    int h = nt * 16 + l15;
    int cb = ksAll * 32 + quad * 8;
    s16x8 v;
    #pragma unroll
    for (int j = 0; j < 8; ++j) v[j] = f2bf(w[(cb + j) * 64 + h] * sc);
    *(s16x8*)&wfrag[((ksAll * 12 + mat * 4 + nt) * 64 + lane) * 8] = v;
}

// ---------------------------------------------------------------------------
// Kernel 2: fused projection, 32 rows/block, x staged coalesced into LDS,
// wfrag B-fragments double-buffered in registers (L2-latency hiding).
// grid 512 x 256 (4 waves = 2 row-tiles x 2 C-halves).
// ---------------------------------------------------------------------------
union ProjSmem {
    short xs[32][1032];                 // staged x rows (bf16); 1032 pad -> 2-way banks
    struct {
        short comb[2][16][136];         // K cols 0..63, Q cols 64..127
        short vsep[64][40];             // V transposed [h][key 0..31 +pad]
    } c;
};

__global__ __launch_bounds__(256, 2) void proj_fused(
    const float* __restrict__ x, const short* __restrict__ wfrag,
    short* __restrict__ qb, short* __restrict__ kfrag, short* __restrict__ vfrag)
{
    __shared__ __align__(16) ProjSmem sm;

    int tid = threadIdx.x;
    int w = tid >> 6, lane = tid & 63;
    int rt = w >> 1, h = w & 1;
    int l15 = lane & 15, quad = lane >> 4;
    int m0 = blockIdx.x * 32;

    // ---- prefetch wfrag set for ks=0 BEFORE staging (flies during stage) ----
    s16x8 fA[12], fB[12];
    {
        const s16x8* fb = (const s16x8*)&wfrag[((size_t)(h * 16) * 12 * 64 + lane) * 8];
        #pragma unroll
        for (int f = 0; f < 12; ++f) fA[f] = fb[f * 64];
    }

    // ---- stage x: 32 passes, each = one full row, lanes along C ----
    #pragma unroll 8
    for (int p = 0; p < 32; ++p) {
        f32x4 v = *(const f32x4*)&x[(size_t)(m0 + p) * C_DIM + tid * 4];
        u32x2 d;
        d[0] = pack2(v[0], v[1]);
        d[1] = pack2(v[2], v[3]);
        *(u32x2*)&sm.xs[p][tid * 4] = d;
    }
    __syncthreads();

    // ---- MFMA with wfrag double-buffer: wave (rt,h), ksAll = h*16+ks ----
    f32x4 acc[12];
    #pragma unroll
    for (int i = 0; i < 12; ++i) acc[i] = (f32x4){0.f, 0.f, 0.f, 0.f};

    #pragma unroll 1
    for (int ks = 0; ks < 16; ks += 2) {
        {   // prefetch ks+1 into fB
            const s16x8* fb = (const s16x8*)&wfrag[((size_t)(h * 16 + ks + 1) * 12 * 64 + lane) * 8];
            #pragma unroll
            for (int f = 0; f < 12; ++f) fB[f] = fb[f * 64];
        }
        s16x8 af = *(const s16x8*)&sm.xs[rt * 16 + l15][(h * 16 + ks) * 32 + quad * 8];
        #pragma unroll
        for (int f = 0; f < 12; ++f)
            acc[f] = __builtin_amdgcn_mfma_f32_16x16x32_bf16(af, fA[f], acc[f], 0, 0, 0);
        if (ks + 2 < 16) {  // prefetch ks+2 into fA
            const s16x8* fb = (const s16x8*)&wfrag[((size_t)(h * 16 + ks + 2) * 12 * 64 + lane) * 8];
            #pragma unroll
            for (int f = 0; f < 12; ++f) fA[f] = fb[f * 64];
        }
        s16x8 af2 = *(const s16x8*)&sm.xs[rt * 16 + l15][(h * 16 + ks + 1) * 32 + quad * 8];
        #pragma unroll
        for (int f = 0; f < 12; ++f)
            acc[f] = __builtin_amdgcn_mfma_f32_16x16x32_bf16(af2, fB[f], acc[f], 0, 0, 0);
    }
    __syncthreads();   // all waves done reading xs; union -> combine buffers

    // ---- combine: h=1 parks, h=0 adds ----
    if (h == 1) {
        #pragma unroll
        for (int f = 0; f < 8; ++f)
            #pragma unroll
            for (int r = 0; r < 4; ++r)
                sm.c.comb[rt][quad * 4 + r][(f >> 2) * 64 + (f & 3) * 16 + l15] = f2bf(acc[f][r]);
        #pragma unroll
        for (int f = 8; f < 12; ++f)
            #pragma unroll
            for (int r = 0; r < 4; ++r)
                sm.c.vsep[(f & 3) * 16 + l15][rt * 16 + quad * 4 + r] = f2bf(acc[f][r]);
    }
    __syncthreads();
    if (h == 0) {
        #pragma unroll
        for (int f = 0; f < 8; ++f)
            #pragma unroll
            for (int r = 0; r < 4; ++r) {
                int col = (f >> 2) * 64 + (f & 3) * 16 + l15, rr = quad * 4 + r;
                sm.c.comb[rt][rr][col] = f2bf(acc[f][r] + bf2f(sm.c.comb[rt][rr][col]));
            }
        #pragma unroll
        for (int f = 8; f < 12; ++f)
            #pragma unroll
            for (int r = 0; r < 4; ++r) {
                int hh = (f & 3) * 16 + l15, kk = rt * 16 + quad * 4 + r;
                sm.c.vsep[hh][kk] = f2bf(acc[f][r] + bf2f(sm.c.vsep[hh][kk]));
            }
    }
    __syncthreads();

    // ---- emission ----
    int b = m0 >> 12, t0 = m0 & 4095;
    int t016 = t0 >> 4, kt32 = t0 >> 5;
    {   // qb: 32 rows x 64 cols
        int row = tid >> 3, ch = tid & 7;
        s16x8 v = *(const s16x8*)&sm.c.comb[row >> 4][row & 15][64 + ch * 8];
        *(s16x8*)&qb[(size_t)(m0 + row) * 64 + ch * 8] = v;
    }
    {   // kfrag: wave task (kt = w&1, ks = w>>1)
        int kt = w & 1, ks = w >> 1;
        s16x8 v = *(const s16x8*)&sm.c.comb[kt][l15][ks * 32 + quad * 8];
        *(s16x8*)&kfrag[(size_t)(((b * 256 + t016 + kt) * 2 + ks) * 64 + lane) * 8] = v;
    }
    {   // vfrag: wave task nt = w
        int nt = w;
        s16x8 v = *(const s16x8*)&sm.c.vsep[nt * 16 + l15][quad * 8];
        *(s16x8*)&vfrag[(size_t)(((b * 128 + kt32) * 4 + nt) * 64 + lane) * 8] = v;
    }
}

// ---------------------------------------------------------------------------
// Kernel 3: flash partials, S^T form, fixed m=0 softmax.
// Block = (128-query strip g, chunk c, batch b), 8 waves = 8 query-substrips
// of ONE batch. K/V chunk (64 KB) async-staged into LDS once per block,
// fragment-linear (conflict-free ds_read_b128). Bias: per-step A/B register
// prefetch from global. k-loop critical path has no global loads.
// grid (32, 16, 4) x 512. po slot: 16x64 O + 16 l bf16 (unchanged layout).
// ---------------------------------------------------------------------------
#define SOFT(N, AS, BV) do {                                                  \
    float _sv[4];                                                             \
    _Pragma("unroll")                                                         \
    for (int _r = 0; _r < 4; ++_r) {                                          \
        _sv[_r] = (AS)[_r] + (BV)[_r];                                        \
        if (mask_on && (kabs + (N) * 16 + quad * 4 + _r > q0 + l15))          \
            _sv[_r] = -__builtin_inff();                                      \
        float _p = __expf(_sv[_r]);                                           \
        _sv[_r] = _p;                                                         \
        l_sum += _p;                                                          \
    }                                                                         \
    u32x2 _d;                                                                 \
    _d[0] = pack2(_sv[0], _sv[1]);                                            \
    _d[1] = pack2(_sv[2], _sv[3]);                                            \
    *(u32x2*)&plds[w][l15][(N) * 16 + quad * 4] = _d;                         \
} while (0)

#define COMPUTEK(KREL, B0, B1) do {                                           \
    int _kt16 = (KREL) >> 4;                                                  \
    int _kt32 = (KREL) >> 5;                                                  \
    int kabs = kstart + (KREL);                                               \
    s16x8 _ak0 = *(const s16x8*)&klds[(_kt16 * 2 + 0) * 512 + lane * 8];      \
    s16x8 _ak1 = *(const s16x8*)&klds[(_kt16 * 2 + 1) * 512 + lane * 8];      \
    s16x8 _ak2 = *(const s16x8*)&klds[(_kt16 * 2 + 2) * 512 + lane * 8];      \
    s16x8 _ak3 = *(const s16x8*)&klds[(_kt16 * 2 + 3) * 512 + lane * 8];      \
    s16x8 _bv0 = *(const s16x8*)&vlds[(_kt32 * 4 + 0) * 512 + lane * 8];      \
    s16x8 _bv1 = *(const s16x8*)&vlds[(_kt32 * 4 + 1) * 512 + lane * 8];      \
    s16x8 _bv2 = *(const s16x8*)&vlds[(_kt32 * 4 + 2) * 512 + lane * 8];      \
    s16x8 _bv3 = *(const s16x8*)&vlds[(_kt32 * 4 + 3) * 512 + lane * 8];      \
    f32x4 _aS0 = (f32x4){0.f, 0.f, 0.f, 0.f};                                 \
    f32x4 _aS1 = (f32x4){0.f, 0.f, 0.f, 0.f};                                 \
    _aS0 = __builtin_amdgcn_mfma_f32_16x16x32_bf16(_ak0, aq0, _aS0, 0, 0, 0); \
    _aS0 = __builtin_amdgcn_mfma_f32_16x16x32_bf16(_ak1, aq1, _aS0, 0, 0, 0); \
    _aS1 = __builtin_amdgcn_mfma_f32_16x16x32_bf16(_ak2, aq0, _aS1, 0, 0, 0); \
    _aS1 = __builtin_amdgcn_mfma_f32_16x16x32_bf16(_ak3, aq1, _aS1, 0, 0, 0); \
    SOFT(0, _aS0, B0);                                                        \
    SOFT(1, _aS1, B1);                                                        \
    s16x8 _ap = *(const s16x8*)&plds[w][l15][quad * 8];                       \
    accO[0] = __builtin_amdgcn_mfma_f32_16x16x32_bf16(_ap, _bv0, accO[0], 0, 0, 0); \
    accO[1] = __builtin_amdgcn_mfma_f32_16x16x32_bf16(_ap, _bv1, accO[1], 0, 0, 0); \
    accO[2] = __builtin_amdgcn_mfma_f32_16x16x32_bf16(_ap, _bv2, accO[2], 0, 0, 0); \
    accO[3] = __builtin_amdgcn_mfma_f32_16x16x32_bf16(_ap, _bv3, accO[3], 0, 0, 0); \
} while (0)

__global__ __launch_bounds__(512, 4) void flash_part(
    const short* __restrict__ qb, const short* __restrict__ kfrag,
    const short* __restrict__ vfrag, const float* __restrict__ bias,
    short* __restrict__ po)
{
    int g = blockIdx.x;                 // 128-query strip (32)
    int c = blockIdx.y;                 // key chunk (16)
    int b = blockIdx.z;                 // batch (4)
    if (c > (g >> 1)) return;           // block-uniform early exit

    __shared__ __align__(16) short klds[32 * 512];   // 16 key-tiles x 2 ks x 512
    __shared__ __align__(16) short vlds[32 * 512];   // 8 kt32 x 4 nt x 512
    __shared__ __align__(16) short plds[8][16][40];

    int tid = threadIdx.x;
    int w = tid >> 6, lane = tid & 63;
    int l15 = lane & 15, quad = lane >> 4;

    int qt = g * 8 + w;                 // 16-query substrip id
    int q0 = qt * 16;
    int kstart = c * CK;
    int kend = min(kstart + CK, q0 + 16);
    int nk = kend - kstart;             // 16..256, always > 0 for real blocks
    bool mask_on = (kend > q0);         // only diagonal chunk masks

    // ---- async-stage K/V chunk into LDS (fragment-linear, 1 KB/wave-inst) ----
    const short* ksrc = kfrag + (size_t)((b * 256 + c * 16) * 2) * 512;
    const short* vsrc = vfrag + (size_t)((b * 128 + c * 8) * 4) * 512;
    #pragma unroll
    for (int i = 0; i < 4; ++i) {
        int seg = i * 8 + w;
        async16(ksrc + (size_t)seg * 512 + lane * 8, &klds[seg * 512]);
    }
    #pragma unroll
    for (int i = 0; i < 4; ++i) {
        int seg = i * 8 + w;
        async16(vsrc + (size_t)seg * 512 + lane * 8, &vlds[seg * 512]);
    }

    // ---- Q fragments + step-0 bias prefetch fly during staging ----
    const short* qrow = qb + (size_t)(b * T_DIM + q0 + l15) * 64;
    s16x8 aq0 = *(const s16x8*)(qrow + quad * 8);
    s16x8 aq1 = *(const s16x8*)(qrow + 32 + quad * 8);
    const float* brow = bias + (size_t)(q0 + l15) * T_DIM + kstart;
    f32x4 bA0 = *(const f32x4*)&brow[quad * 4];
    f32x4 bA1 = *(const f32x4*)&brow[16 + quad * 4];
    f32x4 bB0, bB1;

    float l_sum = 0.f;
    f32x4 accO[4];
    #pragma unroll
    for (int nt = 0; nt < 4; ++nt) accO[nt] = (f32x4){0.f, 0.f, 0.f, 0.f};

    __syncthreads();                    // drains vmcnt(0): LDS staging complete

    // ---- barrier-free k-loop: LDS K/V + prefetched bias only ----
    int krel = 0;
    while (true) {
        int kn = krel + 32;
        bool more = (kn < nk);
        if (more) {
            bB0 = *(const f32x4*)&brow[kn + quad * 4];
            bB1 = *(const f32x4*)&brow[kn + 16 + quad * 4];
        }
        COMPUTEK(krel, bA0, bA1);
        if (!more) break;
        krel = kn; kn = krel + 32;
        bool more2 = (kn < nk);
        if (more2) {
            bA0 = *(const f32x4*)&brow[kn + quad * 4];
            bA1 = *(const f32x4*)&brow[kn + 16 + quad * 4];
        }
        COMPUTEK(krel, bB0, bB1);
        if (!more2) break;
        krel = kn;
    }

    l_sum += __shfl_xor(l_sum, 16, 64);
    l_sum += __shfl_xor(l_sum, 32, 64);

    short* base = po + (size_t)((chunk_off(qt) + c) * 4 + b) * 1040;
    #pragma unroll
    for (int nt = 0; nt < 4; ++nt)
        #pragma unroll
        for (int r = 0; r < 4; ++r)
            base[(quad * 4 + r) * 64 + nt * 16 + l15] = f2bf(accO[nt][r]);
    if (quad == 0) base[1024 + l15] = f2bf(l_sum);
}

// ---------------------------------------------------------------------------
// Kernel 4: reduce partials + normalize. 512 x 256, 16B loads (8 thr/row).
// ---------------------------------------------------------------------------
__global__ __launch_bounds__(256) void flash_reduce(
    const short* __restrict__ po, float* __restrict__ out)
{
    int idx = blockIdx.x * 256 + threadIdx.x;     // 131072 = 16384 rows x 8
    int row = idx >> 3, c8 = idx & 7;
    int b = row >> 12, t = row & 4095;
    int qt = t >> 4, rloc = t & 15;
    int nc = (t >> 8) + 1;
    int off = chunk_off(qt);
    float o[8];
    #pragma unroll
    for (int j = 0; j < 8; ++j) o[j] = 0.f;
    float l = 0.f;
    #pragma unroll 1
    for (int cc = 0; cc < nc; ++cc) {
        const short* base = po + (size_t)((off + cc) * 4 + b) * 1040;
        s16x8 v = *(const s16x8*)&base[rloc * 64 + c8 * 8];
        #pragma unroll
        for (int j = 0; j < 8; ++j) o[j] += bf2f(v[j]);
        l += bf2f(base[1024 + rloc]);
    }
    float inv = 1.0f / l;
    f32x4 r0 = (f32x4){o[0] * inv, o[1] * inv, o[2] * inv, o[3] * inv};
    f32x4 r1 = (f32x4){o[4] * inv, o[5] * inv, o[6] * inv, o[7] * inv};
    float* op = &out[(size_t)row * 64 + c8 * 8];
    *(f32x4*)op = r0;
    *(f32x4*)(op + 4) = r1;
}

// ---------------------------------------------------------------------------
extern "C" void kernel_launch(void* const* d_in, const int* in_sizes, int n_in,
                              void* d_out, int out_size, void* d_ws, size_t ws_size,
                              hipStream_t stream) {
    (void)in_sizes; (void)n_in; (void)out_size; (void)ws_size;
    const float* x    = (const float*)d_in[0];
    const float* bias = (const float*)d_in[1];
    const float* wk   = (const float*)d_in[2];
    const float* wq   = (const float*)d_in[3];
    const float* wv   = (const float*)d_in[4];
    float* out = (float*)d_out;

    short* wfrag = (short*)d_ws;                       // 196608
    short* qb    = wfrag + 196608;                     // 1048576 each
    short* kfrag = qb + 1048576;
    short* vfrag = kfrag + 1048576;
    short* po    = vfrag + 1048576;                    // 2176*4*1040 = 9052160

    prep_frag<<<dim3(32, 3), dim3(256), 0, stream>>>(wk, wq, wv, wfrag);
    proj_fused<<<dim3(512), dim3(256), 0, stream>>>(x, wfrag, qb, kfrag, vfrag);
    flash_part<<<dim3(32, 16, 4), dim3(512), 0, stream>>>(qb, kfrag, vfrag, bias, po);
    flash_reduce<<<dim3(512), dim3(256), 0, stream>>>(po, out);
}